// Round 3
// baseline (73.586 us; speedup 1.0000x reference)
//
#include <hip/hip_runtime.h>
#include <hip/hip_cooperative_groups.h>
#include <math.h>

namespace cg = cooperative_groups;

constexpr int B = 64, L = 2048, D = 1024, P = 512, C = 32;
constexpr int NT = 256;

// One cooperative kernel, two phases separated by grid.sync().
// Phase 1: split-K stage-1 GEMM (X[64x3072] @ W1[3072x512]) -> partial1[NK][64][512]
//   grid = 4 col-tiles x NK k-chunks. CH1 divides 1024.
// Phase 2: blocks 0..63 (one per batch): reduce+tanh -> c1; c1@Whid+tanh -> c2;
//   c2@scorer -> softmax -> out.
template<int CH1>
__global__ __launch_bounds__(NT) void relpred_coop(
    const float* __restrict__ enc, const int* __restrict__ prep_idx,
    const float* __restrict__ Wh, const float* __restrict__ Wp,
    const float* __restrict__ Wc, const float* __restrict__ Whid,
    const float* __restrict__ Wsc, float* __restrict__ out,
    float* __restrict__ partial1)
{
    constexpr int NK  = 3072 / CH1;
    constexpr int CPM = 1024 / CH1;       // chunks per source matrix
    const int tid = threadIdx.x;

    __shared__ float Xt[CH1][68];         // transposed X chunk (+pad)
    __shared__ float Wl[CH1][128];

    // ---------------- phase 1 ----------------
    {
        const int ct = blockIdx.x & 3;            // 0..3 (128 cols)
        const int kc = blockIdx.x >> 2;           // 0..NK-1
        const int m    = kc / CPM;                // 0=head,1=prep,2=child
        const int koff = (kc % CPM) * CH1;
        const float* Wm = (m == 0) ? Wh : (m == 1) ? Wp : Wc;

        // stage W chunk: CH1 x 128, coalesced float4
        for (int i = tid; i < CH1 * 32; i += NT) {
            const int r = i >> 5, c4 = (i & 31) * 4;
            *(float4*)&Wl[r][c4] =
                *(const float4*)&Wm[(size_t)(koff + r) * P + ct * 128 + c4];
        }
        // stage X chunk (gather row prep+m-1 per batch), transposed
        constexpr int QPB = CH1 / 4;
        for (int i = tid; i < 64 * QPB; i += NT) {
            const int b = i / QPB, q = i % QPB;
            const int row = prep_idx[b] + m - 1;
            const float4 v = *(const float4*)&enc[((size_t)b * L + row) * D + koff + q * 4];
            Xt[q*4+0][b] = v.x; Xt[q*4+1][b] = v.y;
            Xt[q*4+2][b] = v.z; Xt[q*4+3][b] = v.w;
        }
        __syncthreads();

        const int ty = tid >> 4, tx = tid & 15;
        float acc[4][8];
        #pragma unroll
        for (int i = 0; i < 4; ++i)
            #pragma unroll
            for (int j = 0; j < 8; ++j) acc[i][j] = 0.f;

        #pragma unroll 4
        for (int k = 0; k < CH1; ++k) {
            const float4 xv = *(float4*)&Xt[k][ty * 4];
            const float4 w0 = *(float4*)&Wl[k][tx * 8];
            const float4 w1 = *(float4*)&Wl[k][tx * 8 + 4];
            const float xs[4]  = {xv.x, xv.y, xv.z, xv.w};
            const float ws8[8] = {w0.x, w0.y, w0.z, w0.w, w1.x, w1.y, w1.z, w1.w};
            #pragma unroll
            for (int i = 0; i < 4; ++i)
                #pragma unroll
                for (int j = 0; j < 8; ++j) acc[i][j] += xs[i] * ws8[j];
        }

        #pragma unroll
        for (int i = 0; i < 4; ++i) {
            const int b = ty * 4 + i;
            const size_t base = ((size_t)kc * B + b) * P + ct * 128 + tx * 8;
            *(float4*)&partial1[base]     = make_float4(acc[i][0], acc[i][1], acc[i][2], acc[i][3]);
            *(float4*)&partial1[base + 4] = make_float4(acc[i][4], acc[i][5], acc[i][6], acc[i][7]);
        }
    }

    cg::this_grid().sync();   // device-scope fence: partial1 visible cross-XCD

    // ---------------- phase 2 ----------------
    if (blockIdx.x < B) {
        const int b = blockIdx.x;
        __shared__ float c1[P];
        __shared__ float c2[P];
        __shared__ float sp[8][C];

        // reduce split-K partials + tanh
        for (int pp = tid; pp < P; pp += NT) {
            float s = 0.f;
            #pragma unroll 8
            for (int kc = 0; kc < NK; ++kc)
                s += partial1[((size_t)kc * B + b) * P + pp];
            c1[pp] = tanhf(s);
        }
        __syncthreads();

        // hidden GEMV: c2 = tanh(c1 @ Whid), 2 q's per thread
        {
            const int q0 = tid, q1 = tid + NT;
            float s0 = 0.f, s1 = 0.f;
            #pragma unroll 8
            for (int p = 0; p < P; ++p) {
                const float cv = c1[p];
                s0 += cv * Whid[(size_t)p * P + q0];
                s1 += cv * Whid[(size_t)p * P + q1];
            }
            c2[q0] = tanhf(s0);
            c2[q1] = tanhf(s1);
        }
        __syncthreads();

        // scorer GEMV + wave softmax
        const int c = tid & (C - 1);
        const int g = tid >> 5;          // 8 groups x 64 p's
        float partial = 0.f;
        #pragma unroll
        for (int k = 0; k < P / 8; ++k) {
            const int p = g * (P / 8) + k;
            partial += c2[p] * Wsc[(size_t)p * C + c];
        }
        sp[g][c] = partial;
        __syncthreads();

        if (tid < C) {
            float score = 0.f;
            #pragma unroll
            for (int gq = 0; gq < 8; ++gq) score += sp[gq][tid];
            float m = score;
            #pragma unroll
            for (int off = 16; off; off >>= 1) m = fmaxf(m, __shfl_xor(m, off));
            const float e = expf(score - m);
            float s = e;
            #pragma unroll
            for (int off = 16; off; off >>= 1) s += __shfl_xor(s, off);
            out[b * C + tid] = e / s;
        }
    }
}

extern "C" void kernel_launch(void* const* d_in, const int* in_sizes, int n_in,
                              void* d_out, int out_size, void* d_ws, size_t ws_size,
                              hipStream_t stream) {
    const float* enc      = (const float*)d_in[0];
    const int*   prep_idx = (const int*)  d_in[1];
    const float* Wh       = (const float*)d_in[2];
    const float* Wp       = (const float*)d_in[3];
    const float* Wc       = (const float*)d_in[4];
    const float* Whid     = (const float*)d_in[5];
    const float* Wsc      = (const float*)d_in[6];
    float*       out      = (float*)d_out;
    float*       partial1 = (float*)d_ws;

    void* args[] = {(void*)&enc, (void*)&prep_idx, (void*)&Wh, (void*)&Wp, (void*)&Wc,
                    (void*)&Whid, (void*)&Wsc, (void*)&out, (void*)&partial1};

    const size_t need48 = (size_t)48 * B * P * sizeof(float);
    if (ws_size >= need48) {
        // CH1=64 -> NK=48, grid = 4*48 = 192 blocks
        hipLaunchCooperativeKernel((const void*)relpred_coop<64>,
                                   dim3(192), dim3(NT), args, 0, stream);
    } else {
        // CH1=128 -> NK=24, grid = 4*24 = 96 blocks (ws 3.1 MB)
        hipLaunchCooperativeKernel((const void*)relpred_coop<128>,
                                   dim3(96), dim3(NT), args, 0, stream);
    }
}